// Round 2
// baseline (38533.896 us; speedup 1.0000x reference)
//
#include <hip/hip_runtime.h>
#include <hip/hip_cooperative_groups.h>

namespace cg = cooperative_groups;

#define D_INX 512
#define NH1   1024
#define NH2   512
#define T_SEQ 256
#define T_TOT 288
#define BATCH 64

__device__ __forceinline__ float sigf(float x) {
    return 1.0f / (1.0f + __expf(-x));
}
__device__ __forceinline__ float tanh_fast(float x) {
    float e = __expf(2.0f * fabsf(x));
    float t = 1.0f - 2.0f / (1.0f + e);
    return copysignf(t, x);
}

#define DOT4(acc, v, wv) \
    acc = fmaf((v).x, (wv).x, acc); \
    acc = fmaf((v).y, (wv).y, acc); \
    acc = fmaf((v).z, (wv).z, acc); \
    acc = fmaf((v).w, (wv).w, acc);

// input [T][B][512] -> xT4[t][k4][b] (float4 of 4 consecutive k per (k4,b))
__global__ void transpose_x(const float* __restrict__ in, float4* __restrict__ xT4) {
    int t = blockIdx.x;
    for (int i = threadIdx.x; i < (D_INX / 4) * BATCH; i += blockDim.x) {
        int b  = i & 63;
        int k4 = i >> 6;
        const float4* p = (const float4*)(in + ((size_t)t * BATCH + b) * D_INX + 4 * k4);
        xT4[(size_t)t * (D_INX / 4) * BATCH + i] = *p;
    }
}

// Persistent cooperative kernel: 256 blocks x 256 threads.
// Wave w (0..3) of block bid owns layer-1 hidden unit j1 = bid*4+w (4 gate rows).
// Layer 2: wave pair (w, w+2) owns j2 = bid*2 + (w&1), split-K via LDS.
__global__ void __launch_bounds__(256, 1)
lstm_seq(const float4* __restrict__ xT4,
         const float4* __restrict__ Wih1, const float4* __restrict__ Whh1,
         const float* __restrict__ bih1, const float* __restrict__ bhh1,
         const float4* __restrict__ Wih2, const float4* __restrict__ Whh2,
         const float* __restrict__ bih2, const float* __restrict__ bhh2,
         float* h1a, float* h1b, float* h2a, float* h2b,
         float* __restrict__ out)
{
    cg::grid_group grid = cg::this_grid();
    const int tid  = threadIdx.x;
    const int lane = tid & 63;
    const int w    = __builtin_amdgcn_readfirstlane(tid >> 6);
    const int bid  = blockIdx.x;

    // ---- layer 1 row assignment ----
    const int j1 = bid * 4 + w;
    float bias1[4];
#pragma unroll
    for (int g = 0; g < 4; ++g) {
        int r = g * NH1 + j1;
        bias1[g] = bih1[r] + bhh1[r];
    }
    const float4* wx0 = Wih1 + (size_t)(0 * NH1 + j1) * (D_INX / 4);
    const float4* wx1 = Wih1 + (size_t)(1 * NH1 + j1) * (D_INX / 4);
    const float4* wx2 = Wih1 + (size_t)(2 * NH1 + j1) * (D_INX / 4);
    const float4* wx3 = Wih1 + (size_t)(3 * NH1 + j1) * (D_INX / 4);
    const float4* wh0 = Whh1 + (size_t)(0 * NH1 + j1) * (NH1 / 4);
    const float4* wh1 = Whh1 + (size_t)(1 * NH1 + j1) * (NH1 / 4);
    const float4* wh2 = Whh1 + (size_t)(2 * NH1 + j1) * (NH1 / 4);
    const float4* wh3 = Whh1 + (size_t)(3 * NH1 + j1) * (NH1 / 4);

    // ---- layer 2 row assignment ----
    const int j2 = bid * 2 + (w & 1);
    float bias2[4];
#pragma unroll
    for (int g = 0; g < 4; ++g) {
        int r = g * NH2 + j2;
        bias2[g] = bih2[r] + bhh2[r];
    }
    const float4* v0 = Wih2 + (size_t)(0 * NH2 + j2) * (NH1 / 4);
    const float4* v1 = Wih2 + (size_t)(1 * NH2 + j2) * (NH1 / 4);
    const float4* v2 = Wih2 + (size_t)(2 * NH2 + j2) * (NH1 / 4);
    const float4* v3 = Wih2 + (size_t)(3 * NH2 + j2) * (NH1 / 4);
    const float4* u0 = Whh2 + (size_t)(0 * NH2 + j2) * (NH2 / 4);
    const float4* u1 = Whh2 + (size_t)(1 * NH2 + j2) * (NH2 / 4);
    const float4* u2 = Whh2 + (size_t)(2 * NH2 + j2) * (NH2 / 4);
    const float4* u3 = Whh2 + (size_t)(3 * NH2 + j2) * (NH2 / 4);

    float c1 = 0.0f, c2 = 0.0f;

    __shared__ float part[2][4][64];

    // zero initial state buffers (ws is poisoned before every launch)
    {
        int gt = bid * 256 + tid;
        h1a[gt] = 0.0f;
        if (gt < NH2 * BATCH) h2a[gt] = 0.0f;
    }
    grid.sync();

    float* h1cur = h1a; float* h1nxt = h1b;
    float* h2cur = h2a; float* h2nxt = h2b;

    for (int t = 0; t < T_TOT; ++t) {
        // ================= layer 1 (all 4 waves) =================
        const float4* xp = (t < T_SEQ) ? (xT4 + (size_t)t * (D_INX / 4) * BATCH)
                                       : (const float4*)h2cur;
        const float4* hp = (const float4*)h1cur;
        float a0 = bias1[0], a1 = bias1[1], a2 = bias1[2], a3 = bias1[3];
#pragma unroll 4
        for (int k = 0; k < D_INX / 4; ++k) {
            float4 xv = xp[k * 64 + lane];
            float4 m0 = wx0[k], m1 = wx1[k], m2 = wx2[k], m3 = wx3[k];
            DOT4(a0, xv, m0); DOT4(a1, xv, m1); DOT4(a2, xv, m2); DOT4(a3, xv, m3);
        }
#pragma unroll 4
        for (int k = 0; k < NH1 / 4; ++k) {
            float4 hv = hp[k * 64 + lane];
            float4 m0 = wh0[k], m1 = wh1[k], m2 = wh2[k], m3 = wh3[k];
            DOT4(a0, hv, m0); DOT4(a1, hv, m1); DOT4(a2, hv, m2); DOT4(a3, hv, m3);
        }
        {
            float iv = sigf(a0), fv = sigf(a1), gv = tanh_fast(a2), ov = sigf(a3);
            c1 = fv * c1 + iv * gv;
            float h1v = ov * tanh_fast(c1);
            h1nxt[((j1 >> 2) << 8) + (lane << 2) + (j1 & 3)] = h1v;
        }

        grid.sync();   // h1nxt visible everywhere

        // ================= layer 2 (wave pairs, split-K) =================
        const float4* h1n4 = (const float4*)h1nxt;
        const float4* h2c4 = (const float4*)h2cur;
        float p0, p1, p2, p3;
        if (w >= 2) {
            p0 = p1 = p2 = p3 = 0.0f;
#pragma unroll 4
            for (int k = 0; k < 192; ++k) {
                float4 hv = h1n4[k * 64 + lane];
                float4 m0 = v0[k], m1 = v1[k], m2 = v2[k], m3 = v3[k];
                DOT4(p0, hv, m0); DOT4(p1, hv, m1); DOT4(p2, hv, m2); DOT4(p3, hv, m3);
            }
            part[w - 2][0][lane] = p0;
            part[w - 2][1][lane] = p1;
            part[w - 2][2][lane] = p2;
            part[w - 2][3][lane] = p3;
        } else {
            p0 = bias2[0]; p1 = bias2[1]; p2 = bias2[2]; p3 = bias2[3];
#pragma unroll 4
            for (int k = 192; k < 256; ++k) {
                float4 hv = h1n4[k * 64 + lane];
                float4 m0 = v0[k], m1 = v1[k], m2 = v2[k], m3 = v3[k];
                DOT4(p0, hv, m0); DOT4(p1, hv, m1); DOT4(p2, hv, m2); DOT4(p3, hv, m3);
            }
#pragma unroll 4
            for (int k = 0; k < NH2 / 4; ++k) {
                float4 hv = h2c4[k * 64 + lane];
                float4 m0 = u0[k], m1 = u1[k], m2 = u2[k], m3 = u3[k];
                DOT4(p0, hv, m0); DOT4(p1, hv, m1); DOT4(p2, hv, m2); DOT4(p3, hv, m3);
            }
        }
        __syncthreads();
        if (w < 2) {
            p0 += part[w][0][lane];
            p1 += part[w][1][lane];
            p2 += part[w][2][lane];
            p3 += part[w][3][lane];
            float i2 = sigf(p0), f2 = sigf(p1), g2 = tanh_fast(p2), o2 = sigf(p3);
            c2 = f2 * c2 + i2 * g2;
            float h2v = o2 * tanh_fast(c2);
            h2nxt[((j2 >> 2) << 8) + (lane << 2) + (j2 & 3)] = h2v;
            out[(size_t)lane * (T_TOT * NH2) + (size_t)t * NH2 + j2] = h2v;
        }

        // Second grid sync needed only once layer-1 starts consuming h2
        // (future phase: read at t+1 >= T_SEQ). Seq-phase hazards are all
        // ordered by the next iteration's first grid.sync.
        if (t >= T_SEQ - 1) grid.sync();

        float* tp = h1cur; h1cur = h1nxt; h1nxt = tp;
        tp = h2cur; h2cur = h2nxt; h2nxt = tp;
    }
}

extern "C" void kernel_launch(void* const* d_in, const int* in_sizes, int n_in,
                              void* d_out, int out_size, void* d_ws, size_t ws_size,
                              hipStream_t stream) {
    const float* input = (const float*)d_in[0];
    const float* W_ih1 = (const float*)d_in[1];
    const float* W_hh1 = (const float*)d_in[2];
    const float* b_ih1 = (const float*)d_in[3];
    const float* b_hh1 = (const float*)d_in[4];
    const float* W_ih2 = (const float*)d_in[5];
    const float* W_hh2 = (const float*)d_in[6];
    const float* b_ih2 = (const float*)d_in[7];
    const float* b_hh2 = (const float*)d_in[8];
    float* out = (float*)d_out;

    float* ws = (float*)d_ws;
    float4* xT4 = (float4*)ws;                       // 256*128*64 float4 = 32 MB
    float* h1a = ws + (size_t)T_SEQ * (D_INX / 4) * BATCH * 4;
    float* h1b = h1a + NH1 * BATCH;
    float* h2a = h1b + NH1 * BATCH;
    float* h2b = h2a + NH2 * BATCH;

    hipLaunchKernelGGL(transpose_x, dim3(T_SEQ), dim3(256), 0, stream, input, xT4);

    const float4* Wih1_4 = (const float4*)W_ih1;
    const float4* Whh1_4 = (const float4*)W_hh1;
    const float4* Wih2_4 = (const float4*)W_ih2;
    const float4* Whh2_4 = (const float4*)W_hh2;

    void* args[] = {
        (void*)&xT4,
        (void*)&Wih1_4, (void*)&Whh1_4, (void*)&b_ih1, (void*)&b_hh1,
        (void*)&Wih2_4, (void*)&Whh2_4, (void*)&b_ih2, (void*)&b_hh2,
        (void*)&h1a, (void*)&h1b, (void*)&h2a, (void*)&h2b,
        (void*)&out
    };
    hipLaunchCooperativeKernel((void*)lstm_seq, dim3(256), dim3(256), args, 0, stream);
}

// Round 3
// 23715.053 us; speedup vs baseline: 1.6249x; 1.6249x over previous
//
#include <hip/hip_runtime.h>
#include <hip/hip_cooperative_groups.h>

namespace cg = cooperative_groups;

#define D_INX 512
#define NH1   1024
#define NH2   512
#define T_SEQ 256
#define T_TOT 288
#define BATCH 64

__device__ __forceinline__ float sigf(float x) {
    return 1.0f / (1.0f + __expf(-x));
}
__device__ __forceinline__ float tanh_fast(float x) {
    float e = __expf(2.0f * fabsf(x));
    float t = 1.0f - 2.0f / (1.0f + e);
    return copysignf(t, x);
}

#define DOT4(acc, v, wv) \
    acc = fmaf((v).x, (wv).x, acc); \
    acc = fmaf((v).y, (wv).y, acc); \
    acc = fmaf((v).z, (wv).z, acc); \
    acc = fmaf((v).w, (wv).w, acc);

// input [T][B][512] -> slot t of otmp region: [k4][b] float4 (4 consecutive k)
__global__ void transpose_x(const float* __restrict__ in, float4* __restrict__ xT4) {
    int t = blockIdx.x;
    for (int i = threadIdx.x; i < (D_INX / 4) * BATCH; i += blockDim.x) {
        int b  = i & 63;
        int k4 = i >> 6;
        const float4* p = (const float4*)(in + ((size_t)t * BATCH + b) * D_INX + 4 * k4);
        xT4[(size_t)t * (D_INX / 4) * BATCH + i] = *p;
    }
}

// otmp [t][j][b] -> out [b][t][j], 64x64 tiles via padded LDS
__global__ void transpose_out(const float* __restrict__ ot, float* __restrict__ out) {
    int t  = blockIdx.x >> 3;
    int jt = blockIdx.x & 7;
    __shared__ float tile[64 * 65];
    const float* src = ot + (size_t)t * (NH2 * BATCH) + jt * 64 * BATCH;
    for (int i = threadIdx.x; i < 4096; i += 256) {
        int jj = i >> 6, bb = i & 63;
        tile[jj * 65 + bb] = src[i];
    }
    __syncthreads();
    for (int i = threadIdx.x; i < 4096; i += 256) {
        int bb = i >> 6, jj = i & 63;
        out[(size_t)bb * (T_TOT * NH2) + (size_t)t * NH2 + jt * 64 + jj] = tile[jj * 65 + bb];
    }
}

// ---- finalize helpers (constant unit index keeps register arrays static) ----
__device__ __forceinline__ void lstm_gate(float s0, float s1, float s2, float s3,
                                          float b0, float b1, float b2, float b3,
                                          float& c, float& h) {
    float iv = sigf(s0 + b0), fv = sigf(s1 + b1);
    float gv = tanh_fast(s2 + b2), ov = sigf(s3 + b3);
    c = fv * c + iv * gv;
    h = ov * tanh_fast(c);
}

// Persistent cooperative kernel: 256 blocks x 512 threads (8 waves).
// Weights LDS-resident. 8-way K-split per layer, LDS tree-reduce.
// Wave u (0..3) owns layer-1 unit j1 = bid*4+u (c1 state). Wave q (0..1)
// owns layer-2 unit j2 = bid*2+q (c2 state).
__global__ void __launch_bounds__(512, 2)
lstm_seq(const float4* xT4, float* otmp,
         const float4* __restrict__ Wih1, const float4* __restrict__ Whh1,
         const float* __restrict__ bih1, const float* __restrict__ bhh1,
         const float4* __restrict__ Wih2, const float4* __restrict__ Whh2,
         const float* __restrict__ bih2, const float* __restrict__ bhh2,
         float* h1a, float* h1b, float* h2a, float* h2b)
{
    cg::grid_group grid = cg::this_grid();
    extern __shared__ float lds[];
    float4* w1  = (float4*)lds;               // 16 rows x 384 f4 = 98304 B
    float4* w2  = (float4*)(lds + 24576);     // 8 rows x 384 f4  = 49152 B
    float4* red = (float4*)(lds + 36864);     // 512 f4           = 8192 B

    const int tid  = threadIdx.x;
    const int lane = tid & 63;
    const int w    = tid >> 6;     // wave 0..7
    const int bid  = blockIdx.x;

    // ---- one-time: preload weights into LDS (coalesced) ----
    for (int i = tid; i < 16 * 384; i += 512) {
        int r = i / 384, k4 = i % 384;
        int u = r >> 2, g = r & 3;
        int grow = g * NH1 + bid * 4 + u;
        w1[i] = (k4 < 128) ? Wih1[(size_t)grow * 128 + k4]
                           : Whh1[(size_t)grow * 256 + (k4 - 128)];
    }
    for (int i = tid; i < 8 * 384; i += 512) {
        int r = i / 384, k4 = i % 384;
        int q = r >> 2, g = r & 3;
        int grow = g * NH2 + bid * 2 + q;
        w2[i] = (k4 < 256) ? Wih2[(size_t)grow * 256 + k4]
                           : Whh2[(size_t)grow * 128 + (k4 - 256)];
    }

    // ---- biases (wave-uniform scalars) ----
    float b1g[4], b2g[4];
    {
        int u = (w < 4) ? w : 0;
#pragma unroll
        for (int g = 0; g < 4; ++g) {
            int r = g * NH1 + bid * 4 + u;
            b1g[g] = bih1[r] + bhh1[r];
        }
        int q = (w < 2) ? w : 0;
#pragma unroll
        for (int g = 0; g < 4; ++g) {
            int r = g * NH2 + bid * 2 + q;
            b2g[g] = bih2[r] + bhh2[r];
        }
    }

    // ---- zero initial states ----
    {
        int gid = bid * 512 + tid;
        if (gid < NH1 * BATCH) h1a[gid] = 0.0f;
        if (gid < NH2 * BATCH) h2a[gid] = 0.0f;
    }
    __syncthreads();
    grid.sync();

    float c1 = 0.0f, c2 = 0.0f;
    float* h1c = h1a; float* h1n = h1b;
    float* h2c = h2a; float* h2n = h2b;

    const int lo = w * 48, hi = lo + 48;   // this wave's K chunk (f4 units)

    for (int t = 0; t < T_TOT; ++t) {
        // ================= layer 1: partial dots over chunk =================
        const float4* xp   = (t < T_SEQ) ? (xT4 + (size_t)t * 8192) : (const float4*)h2c;
        const float4* h1c4 = (const float4*)h1c;
        float a[16];
#pragma unroll
        for (int r = 0; r < 16; ++r) a[r] = 0.0f;

        int xe = (lo < 128) ? ((hi < 128) ? hi : 128) : lo;
        for (int kk = lo; kk < xe; ++kk) {
            float4 av = xp[kk * 64 + lane];
#pragma unroll
            for (int r = 0; r < 16; ++r) { float4 wv = w1[r * 384 + kk]; DOT4(a[r], av, wv); }
        }
        for (int kk = (lo > 128 ? lo : 128); kk < hi; ++kk) {
            float4 av = h1c4[(kk - 128) * 64 + lane];
#pragma unroll
            for (int r = 0; r < 16; ++r) { float4 wv = w1[r * 384 + kk]; DOT4(a[r], av, wv); }
        }

        // ---- L1 reduce: round A (waves 4-7 -> 0-3), units 0,1 then 2,3 ----
        if (w >= 4) {
            red[((w - 4) * 2 + 0) * 64 + lane] = make_float4(a[0], a[1], a[2], a[3]);
            red[((w - 4) * 2 + 1) * 64 + lane] = make_float4(a[4], a[5], a[6], a[7]);
        }
        __syncthreads();
        if (w < 4) {
            float4 p = red[(w * 2 + 0) * 64 + lane];
            a[0] += p.x; a[1] += p.y; a[2] += p.z; a[3] += p.w;
            p = red[(w * 2 + 1) * 64 + lane];
            a[4] += p.x; a[5] += p.y; a[6] += p.z; a[7] += p.w;
        }
        __syncthreads();
        if (w >= 4) {
            red[((w - 4) * 2 + 0) * 64 + lane] = make_float4(a[8],  a[9],  a[10], a[11]);
            red[((w - 4) * 2 + 1) * 64 + lane] = make_float4(a[12], a[13], a[14], a[15]);
        }
        __syncthreads();
        if (w < 4) {
            float4 p = red[(w * 2 + 0) * 64 + lane];
            a[8]  += p.x; a[9]  += p.y; a[10] += p.z; a[11] += p.w;
            p = red[(w * 2 + 1) * 64 + lane];
            a[12] += p.x; a[13] += p.y; a[14] += p.z; a[15] += p.w;
        }
        __syncthreads();
        // ---- round B0: units 0,1 finalized by waves 0,1 ----
        if (w < 4) {
            red[(w * 2 + 0) * 64 + lane] = make_float4(a[0], a[1], a[2], a[3]);
            red[(w * 2 + 1) * 64 + lane] = make_float4(a[4], a[5], a[6], a[7]);
        }
        __syncthreads();
        if (w == 0) {
            float s0 = a[0], s1 = a[1], s2 = a[2], s3 = a[3];
#pragma unroll
            for (int w1i = 1; w1i < 4; ++w1i) {
                float4 p = red[(w1i * 2 + 0) * 64 + lane];
                s0 += p.x; s1 += p.y; s2 += p.z; s3 += p.w;
            }
            float hv; lstm_gate(s0, s1, s2, s3, b1g[0], b1g[1], b1g[2], b1g[3], c1, hv);
            h1n[bid * 256 + lane * 4 + 0] = hv;
        } else if (w == 1) {
            float s0 = a[4], s1 = a[5], s2 = a[6], s3 = a[7];
#pragma unroll
            for (int w1i = 0; w1i < 4; ++w1i) {
                if (w1i == 1) continue;
                float4 p = red[(w1i * 2 + 1) * 64 + lane];
                s0 += p.x; s1 += p.y; s2 += p.z; s3 += p.w;
            }
            float hv; lstm_gate(s0, s1, s2, s3, b1g[0], b1g[1], b1g[2], b1g[3], c1, hv);
            h1n[bid * 256 + lane * 4 + 1] = hv;
        }
        __syncthreads();
        // ---- round B1: units 2,3 finalized by waves 2,3 ----
        if (w < 4) {
            red[(w * 2 + 0) * 64 + lane] = make_float4(a[8],  a[9],  a[10], a[11]);
            red[(w * 2 + 1) * 64 + lane] = make_float4(a[12], a[13], a[14], a[15]);
        }
        __syncthreads();
        if (w == 2) {
            float s0 = a[8], s1 = a[9], s2 = a[10], s3 = a[11];
#pragma unroll
            for (int w1i = 0; w1i < 4; ++w1i) {
                if (w1i == 2) continue;
                float4 p = red[(w1i * 2 + 0) * 64 + lane];
                s0 += p.x; s1 += p.y; s2 += p.z; s3 += p.w;
            }
            float hv; lstm_gate(s0, s1, s2, s3, b1g[0], b1g[1], b1g[2], b1g[3], c1, hv);
            h1n[bid * 256 + lane * 4 + 2] = hv;
        } else if (w == 3) {
            float s0 = a[12], s1 = a[13], s2 = a[14], s3 = a[15];
#pragma unroll
            for (int w1i = 0; w1i < 3; ++w1i) {
                float4 p = red[(w1i * 2 + 1) * 64 + lane];
                s0 += p.x; s1 += p.y; s2 += p.z; s3 += p.w;
            }
            float hv; lstm_gate(s0, s1, s2, s3, b1g[0], b1g[1], b1g[2], b1g[3], c1, hv);
            h1n[bid * 256 + lane * 4 + 3] = hv;
        }

        grid.sync();   // h1n visible everywhere

        // ================= layer 2: partial dots over chunk =================
        const float4* h1n4 = (const float4*)h1n;
        const float4* h2c4 = (const float4*)h2c;
        float a2[8];
#pragma unroll
        for (int r = 0; r < 8; ++r) a2[r] = 0.0f;

        int he = (lo < 256) ? ((hi < 256) ? hi : 256) : lo;
        for (int kk = lo; kk < he; ++kk) {
            float4 av = h1n4[kk * 64 + lane];
#pragma unroll
            for (int r = 0; r < 8; ++r) { float4 wv = w2[r * 384 + kk]; DOT4(a2[r], av, wv); }
        }
        for (int kk = (lo > 256 ? lo : 256); kk < hi; ++kk) {
            float4 av = h2c4[(kk - 256) * 64 + lane];
#pragma unroll
            for (int r = 0; r < 8; ++r) { float4 wv = w2[r * 384 + kk]; DOT4(a2[r], av, wv); }
        }

        // ---- L2 reduce: round A ----
        if (w >= 4) {
            red[((w - 4) * 2 + 0) * 64 + lane] = make_float4(a2[0], a2[1], a2[2], a2[3]);
            red[((w - 4) * 2 + 1) * 64 + lane] = make_float4(a2[4], a2[5], a2[6], a2[7]);
        }
        __syncthreads();
        if (w < 4) {
            float4 p = red[(w * 2 + 0) * 64 + lane];
            a2[0] += p.x; a2[1] += p.y; a2[2] += p.z; a2[3] += p.w;
            p = red[(w * 2 + 1) * 64 + lane];
            a2[4] += p.x; a2[5] += p.y; a2[6] += p.z; a2[7] += p.w;
        }
        __syncthreads();
        // ---- round B ----
        if (w < 4) {
            red[(w * 2 + 0) * 64 + lane] = make_float4(a2[0], a2[1], a2[2], a2[3]);
            red[(w * 2 + 1) * 64 + lane] = make_float4(a2[4], a2[5], a2[6], a2[7]);
        }
        __syncthreads();
        if (w == 0) {
            float s0 = a2[0], s1 = a2[1], s2 = a2[2], s3 = a2[3];
#pragma unroll
            for (int w1i = 1; w1i < 4; ++w1i) {
                float4 p = red[(w1i * 2 + 0) * 64 + lane];
                s0 += p.x; s1 += p.y; s2 += p.z; s3 += p.w;
            }
            float hv; lstm_gate(s0, s1, s2, s3, b2g[0], b2g[1], b2g[2], b2g[3], c2, hv);
            h2n[(bid >> 1) * 256 + lane * 4 + ((bid & 1) * 2 + 0)] = hv;
            otmp[(size_t)t * (NH2 * BATCH) + (bid * 2 + 0) * 64 + lane] = hv;
        } else if (w == 1) {
            float s0 = a2[4], s1 = a2[5], s2 = a2[6], s3 = a2[7];
#pragma unroll
            for (int w1i = 0; w1i < 4; ++w1i) {
                if (w1i == 1) continue;
                float4 p = red[(w1i * 2 + 1) * 64 + lane];
                s0 += p.x; s1 += p.y; s2 += p.z; s3 += p.w;
            }
            float hv; lstm_gate(s0, s1, s2, s3, b2g[0], b2g[1], b2g[2], b2g[3], c2, hv);
            h2n[(bid >> 1) * 256 + lane * 4 + ((bid & 1) * 2 + 1)] = hv;
            otmp[(size_t)t * (NH2 * BATCH) + (bid * 2 + 1) * 64 + lane] = hv;
        }
        __syncthreads();   // red reused by next step's L1 round A

        // future phase: next layer-1 consumes h2n -> need full grid order
        if (t >= T_SEQ - 1) grid.sync();

        float* tp = h1c; h1c = h1n; h1n = tp;
        tp = h2c; h2c = h2n; h2n = tp;
    }
}

extern "C" void kernel_launch(void* const* d_in, const int* in_sizes, int n_in,
                              void* d_out, int out_size, void* d_ws, size_t ws_size,
                              hipStream_t stream) {
    const float* input = (const float*)d_in[0];
    const float* W_ih1 = (const float*)d_in[1];
    const float* W_hh1 = (const float*)d_in[2];
    const float* b_ih1 = (const float*)d_in[3];
    const float* b_hh1 = (const float*)d_in[4];
    const float* W_ih2 = (const float*)d_in[5];
    const float* W_hh2 = (const float*)d_in[6];
    const float* b_ih2 = (const float*)d_in[7];
    const float* b_hh2 = (const float*)d_in[8];
    float* out = (float*)d_out;

    // ws layout (floats):
    // [0]                otmp: 288 slots x 32768 (slots 0..255 double as xT4)
    // [288*32768]        h1a, h1b (65536 each), h2a, h2b (32768 each)
    float* ws   = (float*)d_ws;
    float* otmp = ws;
    float4* xT4 = (float4*)ws;
    float* h1a  = ws + (size_t)T_TOT * NH2 * BATCH;
    float* h1b  = h1a + NH1 * BATCH;
    float* h2a  = h1b + NH1 * BATCH;
    float* h2b  = h2a + NH2 * BATCH;

    hipLaunchKernelGGL(transpose_x, dim3(T_SEQ), dim3(256), 0, stream, input, xT4);

    const float4* Wih1_4 = (const float4*)W_ih1;
    const float4* Whh1_4 = (const float4*)W_hh1;
    const float4* Wih2_4 = (const float4*)W_ih2;
    const float4* Whh2_4 = (const float4*)W_hh2;

    static bool attr_set = false;
    (void)attr_set;
    hipFuncSetAttribute((const void*)lstm_seq,
                        hipFuncAttributeMaxDynamicSharedMemorySize, 155648);

    void* args[] = {
        (void*)&xT4, (void*)&otmp,
        (void*)&Wih1_4, (void*)&Whh1_4, (void*)&b_ih1, (void*)&b_hh1,
        (void*)&Wih2_4, (void*)&Whh2_4, (void*)&b_ih2, (void*)&b_hh2,
        (void*)&h1a, (void*)&h1b, (void*)&h2a, (void*)&h2b
    };
    hipLaunchCooperativeKernel((void*)lstm_seq, dim3(256), dim3(512), args,
                               155648, stream);

    hipLaunchKernelGGL(transpose_out, dim3(T_TOT * 8), dim3(256), 0, stream,
                       (const float*)otmp, out);
}

// Round 4
// 13440.353 us; speedup vs baseline: 2.8670x; 1.7645x over previous
//
#include <hip/hip_runtime.h>
#include <hip/hip_bf16.h>
#include <hip/hip_cooperative_groups.h>

namespace cg = cooperative_groups;

#define NH1   1024
#define NH2   512
#define T_SEQ 256
#define T_TOT 288

typedef short short8 __attribute__((ext_vector_type(8)));
typedef float f32x4 __attribute__((ext_vector_type(4)));

union FragU { short8 s; unsigned short u[8]; };

__device__ __forceinline__ unsigned short f2bf(float x) {
    __hip_bfloat16 b = __float2bfloat16(x);
    return __builtin_bit_cast(unsigned short, b);
}
__device__ __forceinline__ float bf2f(unsigned short u) {
    unsigned int v = ((unsigned int)u) << 16;
    return __builtin_bit_cast(float, v);
}
__device__ __forceinline__ float sigf(float x) {
    return 1.0f / (1.0f + __expf(-x));
}
__device__ __forceinline__ float tanh_fast(float x) {
    float e = __expf(2.0f * fabsf(x));
    float t = 1.0f - 2.0f / (1.0f + e);
    return copysignf(t, x);
}

// input [T][B=64][512] fp32 -> xThi/xTlo [t][k8=64][b=64][8] bf16 (hi + residual lo)
__global__ void prep_x(const float* __restrict__ in,
                       unsigned short* __restrict__ xThi,
                       unsigned short* __restrict__ xTlo) {
    int t = blockIdx.x;
    const float* src = in + (size_t)t * (64 * 512);
    for (int idx = threadIdx.x; idx < 4096; idx += 256) {
        int k8 = idx >> 6, b = idx & 63;
        FragU hi, lo;
#pragma unroll
        for (int i = 0; i < 8; ++i) {
            float v = src[b * 512 + k8 * 8 + i];
            unsigned short h = f2bf(v);
            hi.u[i] = h;
            lo.u[i] = f2bf(v - bf2f(h));
        }
        size_t o = (size_t)t * 32768 + (size_t)k8 * 512 + b * 8;
        *(short8*)(xThi + o) = hi.s;
        *(short8*)(xTlo + o) = lo.s;
    }
}

// Persistent cooperative kernel: 256 blocks x 512 threads (8 waves).
// Block bid owns 4 L1 units (16 gate-rows, unit-major: row = u*4+gate) and
// 2 L2 units (8 gate-rows). Wave w takes K-slice [w*192, w*192+192).
// MFMA 16x16x32 bf16, 3-product hi/lo split for ~fp32 accuracy.
// A-frag: lane holds W[row=lane&15][k0+(lane>>4)*8+i]  (loaded once, VGPRs).
// B-frag: lane holds act[k0+(lane>>4)*8+i][col=lane&15] from k8-interleaved
//         global layout [k>>3][b][k&7] -> 4x256B contiguous per load.
// C/D: col=lane&15, row=(lane>>4)*4+reg  => lane's 4 acc regs are exactly
//      gates i,f,g,o of unit (lane>>4) for one batch col. No cross-lane fixup.
__global__ void __launch_bounds__(512, 2)
lstm_mfma(const float* __restrict__ Wih1, const float* __restrict__ Whh1,
          const float* __restrict__ bih1, const float* __restrict__ bhh1,
          const float* __restrict__ Wih2, const float* __restrict__ Whh2,
          const float* __restrict__ bih2, const float* __restrict__ bhh2,
          unsigned short* ws_us, float* __restrict__ out)
{
    cg::grid_group grid = cg::this_grid();
    __shared__ f32x4 red[2048];   // 8 partials x 4 N-tiles x 64 lanes = 32KB

    const int tid  = threadIdx.x;
    const int lane = tid & 63;
    const int w    = tid >> 6;      // wave 0..7
    const int bid  = blockIdx.x;
    const int lhi  = lane >> 4;     // 0..3
    const int llo  = lane & 15;

    // ---- workspace carve (ushort units) ----
    unsigned short* xThi  = ws_us;
    unsigned short* xTlo  = xThi + 8388608;
    unsigned short* h1Ahi = xTlo + 8388608;
    unsigned short* h1Alo = h1Ahi + 65536;
    unsigned short* h1Bhi = h1Alo + 65536;
    unsigned short* h1Blo = h1Bhi + 65536;
    unsigned short* h2Ahi = h1Blo + 65536;
    unsigned short* h2Alo = h2Ahi + 32768;
    unsigned short* h2Bhi = h2Alo + 32768;
    unsigned short* h2Blo = h2Bhi + 32768;

    // ---- zero all state buffers (ws is poisoned each launch) ----
    {
        unsigned int* z = (unsigned int*)h1Ahi;   // 196608 u32 total
        int gid = bid * 512 + tid;                // 131072 threads
        z[gid] = 0u;
        if (gid < 65536) z[gid + 131072] = 0u;
    }

    // ---- one-time: weights -> per-lane A-fragments (hi/lo bf16) ----
    const int wK = w * 192;
    short8 A1h[6], A1l[6], A2h[6], A2l[6];
    {
        int r  = llo;
        int G1 = (r & 3) * NH1 + bid * 4 + (r >> 2);
#pragma unroll
        for (int s = 0; s < 6; ++s) {
            int k = wK + s * 32 + lhi * 8;
            const float* src = (k < 512) ? (Wih1 + (size_t)G1 * 512 + k)
                                         : (Whh1 + (size_t)G1 * 1024 + (k - 512));
            FragU h, l;
#pragma unroll
            for (int i = 0; i < 8; ++i) {
                float v = src[i];
                unsigned short hb = f2bf(v);
                h.u[i] = hb;
                l.u[i] = f2bf(v - bf2f(hb));
            }
            A1h[s] = h.s; A1l[s] = l.s;
        }
        bool valid2 = (r >> 2) < 2;   // only 8 real L2 rows; 8..15 are zero pad
        int G2 = (r & 3) * NH2 + bid * 2 + ((r >> 2) < 2 ? (r >> 2) : 0);
#pragma unroll
        for (int s = 0; s < 6; ++s) {
            FragU h, l;
#pragma unroll
            for (int i = 0; i < 8; ++i) { h.u[i] = 0; l.u[i] = 0; }
            if (valid2) {
                int k = wK + s * 32 + lhi * 8;
                const float* src = (k < 1024) ? (Wih2 + (size_t)G2 * 1024 + k)
                                              : (Whh2 + (size_t)G2 * 512 + (k - 1024));
#pragma unroll
                for (int i = 0; i < 8; ++i) {
                    float v = src[i];
                    unsigned short hb = f2bf(v);
                    h.u[i] = hb;
                    l.u[i] = f2bf(v - bf2f(hb));
                }
            }
            A2h[s] = h.s; A2l[s] = l.s;
        }
    }

    // ---- biases: lane's unit is lhi (L1) / lhi<2 (L2) ----
    float b1[4], b2[4];
#pragma unroll
    for (int g = 0; g < 4; ++g) {
        int r1 = g * NH1 + bid * 4 + lhi;
        b1[g] = bih1[r1] + bhh1[r1];
        int r2 = g * NH2 + bid * 2 + ((lhi < 2) ? lhi : 0);
        b2[g] = bih2[r2] + bhh2[r2];
    }

    const int laneoff = lhi * 512 + llo * 8;   // ushort offset within a k8-slab

    float c1 = 0.0f, c2 = 0.0f;
    unsigned short *h1c_hi = h1Ahi, *h1c_lo = h1Alo, *h1n_hi = h1Bhi, *h1n_lo = h1Blo;
    unsigned short *h2c_hi = h2Ahi, *h2c_lo = h2Alo, *h2n_hi = h2Bhi, *h2n_lo = h2Blo;

    grid.sync();   // states zeroed everywhere

    for (int t = 0; t < T_TOT; ++t) {
        const bool seq = (t < T_SEQ);

        // ================= Layer 1: K-slice partial via MFMA =================
        f32x4 acc[4] = {{0,0,0,0},{0,0,0,0},{0,0,0,0},{0,0,0,0}};
#pragma unroll
        for (int s = 0; s < 6; ++s) {
            int k0 = wK + s * 32;
            const unsigned short *bh, *bl;
            if (seq) {
                if (k0 < 512) { size_t o = (size_t)t * 32768 + (size_t)(k0 >> 3) * 512; bh = xThi + o; bl = xTlo + o; }
                else          { int o = ((k0 - 512) >> 3) * 512; bh = h1c_hi + o; bl = h1c_lo + o; }
            } else {
                if (k0 < 512) { int o = (k0 >> 3) * 512; bh = h2c_hi + o; bl = h2c_lo + o; }
                else          { int o = ((k0 - 512) >> 3) * 512; bh = h1c_hi + o; bl = h1c_lo + o; }
            }
            const short8* ph = (const short8*)(bh + laneoff);
            const short8* pl = (const short8*)(bl + laneoff);
#pragma unroll
            for (int nt = 0; nt < 4; ++nt) {
                short8 Bh = ph[nt * 16];
                short8 Bl = pl[nt * 16];
                acc[nt] = __builtin_amdgcn_mfma_f32_16x16x32_bf16(A1h[s], Bh, acc[nt], 0, 0, 0);
                acc[nt] = __builtin_amdgcn_mfma_f32_16x16x32_bf16(A1l[s], Bh, acc[nt], 0, 0, 0);
                acc[nt] = __builtin_amdgcn_mfma_f32_16x16x32_bf16(A1h[s], Bl, acc[nt], 0, 0, 0);
            }
        }
        // ---- reduce 8 K-partials in LDS; wave nt finalizes batch tile nt ----
#pragma unroll
        for (int nt = 0; nt < 4; ++nt) red[(w * 4 + nt) * 64 + lane] = acc[nt];
        __syncthreads();
        if (w < 4) {
            f32x4 g = red[w * 64 + lane];
#pragma unroll
            for (int p = 1; p < 8; ++p) {
                f32x4 q = red[(p * 4 + w) * 64 + lane];
                g.x += q.x; g.y += q.y; g.z += q.z; g.w += q.w;
            }
            float iv = sigf(g.x + b1[0]);
            float fv = sigf(g.y + b1[1]);
            float gv = tanh_fast(g.z + b1[2]);
            float ov = sigf(g.w + b1[3]);
            c1 = fv * c1 + iv * gv;
            float h = ov * tanh_fast(c1);
            int b = w * 16 + llo;
            int j = bid * 4 + lhi;
            unsigned short hh = f2bf(h);
            unsigned short hl = f2bf(h - bf2f(hh));
            int o = (j >> 3) * 512 + b * 8 + (j & 7);
            h1n_hi[o] = hh; h1n_lo[o] = hl;
        }
        grid.sync();   // h1n visible to all blocks (also orders red reuse)

        // ================= Layer 2 =================
        f32x4 ac2[4] = {{0,0,0,0},{0,0,0,0},{0,0,0,0},{0,0,0,0}};
#pragma unroll
        for (int s = 0; s < 6; ++s) {
            int k0 = wK + s * 32;
            const unsigned short *bh, *bl;
            if (k0 < 1024) { int o = (k0 >> 3) * 512; bh = h1n_hi + o; bl = h1n_lo + o; }
            else           { int o = ((k0 - 1024) >> 3) * 512; bh = h2c_hi + o; bl = h2c_lo + o; }
            const short8* ph = (const short8*)(bh + laneoff);
            const short8* pl = (const short8*)(bl + laneoff);
#pragma unroll
            for (int nt = 0; nt < 4; ++nt) {
                short8 Bh = ph[nt * 16];
                short8 Bl = pl[nt * 16];
                ac2[nt] = __builtin_amdgcn_mfma_f32_16x16x32_bf16(A2h[s], Bh, ac2[nt], 0, 0, 0);
                ac2[nt] = __builtin_amdgcn_mfma_f32_16x16x32_bf16(A2l[s], Bh, ac2[nt], 0, 0, 0);
                ac2[nt] = __builtin_amdgcn_mfma_f32_16x16x32_bf16(A2h[s], Bl, ac2[nt], 0, 0, 0);
            }
        }
#pragma unroll
        for (int nt = 0; nt < 4; ++nt) red[(w * 4 + nt) * 64 + lane] = ac2[nt];
        __syncthreads();
        if (w < 4) {
            f32x4 g = red[w * 64 + lane];
#pragma unroll
            for (int p = 1; p < 8; ++p) {
                f32x4 q = red[(p * 4 + w) * 64 + lane];
                g.x += q.x; g.y += q.y; g.z += q.z; g.w += q.w;
            }
            if (lhi < 2) {
                float iv = sigf(g.x + b2[0]);
                float fv = sigf(g.y + b2[1]);
                float gv = tanh_fast(g.z + b2[2]);
                float ov = sigf(g.w + b2[3]);
                c2 = fv * c2 + iv * gv;
                float h = ov * tanh_fast(c2);
                int b  = w * 16 + llo;
                int j2 = bid * 2 + lhi;
                unsigned short hh = f2bf(h);
                unsigned short hl = f2bf(h - bf2f(hh));
                int o = (j2 >> 3) * 512 + b * 8 + (j2 & 7);
                h2n_hi[o] = hh; h2n_lo[o] = hl;
                out[(size_t)b * (T_TOT * NH2) + (size_t)t * NH2 + j2] = h;
            }
        }
        __syncthreads();   // red reads done before next step's L1 writes

        // future phase: next L1 consumes h2n -> full grid ordering needed
        if (t >= T_SEQ - 1) grid.sync();

        unsigned short* tp;
        tp = h1c_hi; h1c_hi = h1n_hi; h1n_hi = tp;
        tp = h1c_lo; h1c_lo = h1n_lo; h1n_lo = tp;
        tp = h2c_hi; h2c_hi = h2n_hi; h2n_hi = tp;
        tp = h2c_lo; h2c_lo = h2n_lo; h2n_lo = tp;
    }
}

extern "C" void kernel_launch(void* const* d_in, const int* in_sizes, int n_in,
                              void* d_out, int out_size, void* d_ws, size_t ws_size,
                              hipStream_t stream) {
    const float* input = (const float*)d_in[0];
    const float* W_ih1 = (const float*)d_in[1];
    const float* W_hh1 = (const float*)d_in[2];
    const float* b_ih1 = (const float*)d_in[3];
    const float* b_hh1 = (const float*)d_in[4];
    const float* W_ih2 = (const float*)d_in[5];
    const float* W_hh2 = (const float*)d_in[6];
    const float* b_ih2 = (const float*)d_in[7];
    const float* b_hh2 = (const float*)d_in[8];
    float* out = (float*)d_out;

    unsigned short* ws_us = (unsigned short*)d_ws;
    unsigned short* xThi  = ws_us;
    unsigned short* xTlo  = xThi + 8388608;

    hipLaunchKernelGGL(prep_x, dim3(T_SEQ), dim3(256), 0, stream, input, xThi, xTlo);

    void* args[] = {
        (void*)&W_ih1, (void*)&W_hh1, (void*)&b_ih1, (void*)&b_hh1,
        (void*)&W_ih2, (void*)&W_hh2, (void*)&b_ih2, (void*)&b_hh2,
        (void*)&ws_us, (void*)&out
    };
    hipLaunchCooperativeKernel((void*)lstm_mfma, dim3(256), dim3(512), args, 0, stream);
}